// Round 1
// baseline (484.780 us; speedup 1.0000x reference)
//
#include <hip/hip_runtime.h>
#include <hip/hip_bf16.h>
#include <stdint.h>

typedef unsigned short u16;
typedef unsigned int u32;
typedef __bf16 bf16x8 __attribute__((ext_vector_type(8)));
typedef float f32x4 __attribute__((ext_vector_type(4)));

#define B_   2
#define S_   2048
#define D_   1024
#define H_   16
#define HD_  64
#define MTOT 4096

__device__ __forceinline__ u16 f2bf(float f) {
    u32 u = __float_as_uint(f);
    u32 r = (u + 0x7FFFu + ((u >> 16) & 1u)) >> 16;   // RNE; inputs never NaN/Inf
    return (u16)r;
}
__device__ __forceinline__ float bf2f(u16 s) { return __uint_as_float(((u32)s) << 16); }

__device__ __forceinline__ f32x4 mfma16(bf16x8 a, bf16x8 b, f32x4 c) {
    return __builtin_amdgcn_mfma_f32_16x16x32_bf16(a, b, c, 0, 0, 0);
}

// ---------------------------------------------------------------------------
// Split fp32 -> (hi, lo) bf16 pair, elementwise (for x)
// ---------------------------------------------------------------------------
__global__ void split_x_kernel(const float* __restrict__ x,
                               u16* __restrict__ hi, u16* __restrict__ lo, int n4) {
    int i = blockIdx.x * blockDim.x + threadIdx.x;
    if (i >= n4) return;
    float4 v = reinterpret_cast<const float4*>(x)[i];
    u16 h0 = f2bf(v.x), h1 = f2bf(v.y), h2 = f2bf(v.z), h3 = f2bf(v.w);
    u16 l0 = f2bf(v.x - bf2f(h0)), l1 = f2bf(v.y - bf2f(h1));
    u16 l2 = f2bf(v.z - bf2f(h2)), l3 = f2bf(v.w - bf2f(h3));
    uint2 hp, lp;
    hp.x = (u32)h0 | ((u32)h1 << 16); hp.y = (u32)h2 | ((u32)h3 << 16);
    lp.x = (u32)l0 | ((u32)l1 << 16); lp.y = (u32)l2 | ((u32)l3 << 16);
    reinterpret_cast<uint2*>(hi)[i] = hp;
    reinterpret_cast<uint2*>(lo)[i] = lp;
}

// ---------------------------------------------------------------------------
// Split + transpose a [in=1024][out=1024] weight -> wT hi/lo [out][in]
// ---------------------------------------------------------------------------
__global__ void split_w_kernel(const float* __restrict__ w,
                               u16* __restrict__ thi, u16* __restrict__ tlo) {
    __shared__ float tile[32][33];
    int bi = blockIdx.y;   // input-dim block
    int bj = blockIdx.x;   // output-dim block
    int tx = threadIdx.x;  // 0..31
    int ty = threadIdx.y;  // 0..7
#pragma unroll
    for (int k = 0; k < 4; k++) {
        int r = ty + k * 8;
        tile[r][tx] = w[(size_t)(bi * 32 + r) * D_ + bj * 32 + tx];
    }
    __syncthreads();
#pragma unroll
    for (int k = 0; k < 4; k++) {
        int r = ty + k * 8;
        float v = tile[tx][r];
        u16 h = f2bf(v);
        u16 l = f2bf(v - bf2f(h));
        size_t idx = (size_t)(bj * 32 + r) * D_ + bi * 32 + tx;
        thi[idx] = h;
        tlo[idx] = l;
    }
}

// ---------------------------------------------------------------------------
// Split-bf16 GEMM: C = A @ B^T(stored row-major [N][K]) with hi/lo operands.
// MODE 0: q proj (+LIF, layout [bh][s][d])
// MODE 1: k proj (+LIF, layout [bh][s][d])
// MODE 2: v proj (+LIF, layout [bh][d][s]  -- transposed)
// MODE 3: o proj (+bias, fp32 out [4096][1024])
// Tile 128x128, BK=32, 4 waves (each 64x64), reg-staged LDS.
// ---------------------------------------------------------------------------
template <int MODE>
__global__ __launch_bounds__(256, 2)
void gemm_kernel(const u16* __restrict__ Ahg, const u16* __restrict__ Alg,
                 const u16* __restrict__ Bhg, const u16* __restrict__ Blg,
                 const float* __restrict__ bias, void* __restrict__ outp) {
    __shared__ __align__(16) u16 lAh[128 * 32];
    __shared__ __align__(16) u16 lAl[128 * 32];
    __shared__ __align__(16) u16 lBh[128 * 32];
    __shared__ __align__(16) u16 lBl[128 * 32];

    const int t = threadIdx.x;
    const int m0 = blockIdx.y * 128;
    const int n0 = blockIdx.x * 128;
    const int wid = t >> 6, lane = t & 63;
    const int wm = wid >> 1, wn = wid & 1;
    const int lr = lane & 15, lg = lane >> 4;

    f32x4 acc[4][4] = {};
    uint4 rg[8];

    // prologue: load k=0 stage regs
    {
#pragma unroll
        for (int p = 0; p < 2; p++) {
            int idx = t + p * 256;
            int row = idx >> 2, sl = idx & 3;
            size_t ga = (size_t)(m0 + row) * D_ + sl * 8;
            size_t gb = (size_t)(n0 + row) * D_ + sl * 8;
            rg[p * 4 + 0] = *reinterpret_cast<const uint4*>(Ahg + ga);
            rg[p * 4 + 1] = *reinterpret_cast<const uint4*>(Alg + ga);
            rg[p * 4 + 2] = *reinterpret_cast<const uint4*>(Bhg + gb);
            rg[p * 4 + 3] = *reinterpret_cast<const uint4*>(Blg + gb);
        }
    }

    for (int kk = 0; kk < 32; ++kk) {
        __syncthreads();  // previous iter's frag reads complete
#pragma unroll
        for (int p = 0; p < 2; p++) {
            int idx = t + p * 256;
            *reinterpret_cast<uint4*>(lAh + idx * 8) = rg[p * 4 + 0];
            *reinterpret_cast<uint4*>(lAl + idx * 8) = rg[p * 4 + 1];
            *reinterpret_cast<uint4*>(lBh + idx * 8) = rg[p * 4 + 2];
            *reinterpret_cast<uint4*>(lBl + idx * 8) = rg[p * 4 + 3];
        }
        __syncthreads();
        if (kk < 31) {
            int k0 = (kk + 1) * 32;
#pragma unroll
            for (int p = 0; p < 2; p++) {
                int idx = t + p * 256;
                int row = idx >> 2, sl = idx & 3;
                size_t ga = (size_t)(m0 + row) * D_ + k0 + sl * 8;
                size_t gb = (size_t)(n0 + row) * D_ + k0 + sl * 8;
                rg[p * 4 + 0] = *reinterpret_cast<const uint4*>(Ahg + ga);
                rg[p * 4 + 1] = *reinterpret_cast<const uint4*>(Alg + ga);
                rg[p * 4 + 2] = *reinterpret_cast<const uint4*>(Bhg + gb);
                rg[p * 4 + 3] = *reinterpret_cast<const uint4*>(Blg + gb);
            }
        }
        bf16x8 ah[4], al[4], bh[4], bl[4];
#pragma unroll
        for (int m = 0; m < 4; m++) {
            int off = (wm * 64 + m * 16 + lr) * 32 + lg * 8;
            ah[m] = *reinterpret_cast<const bf16x8*>(lAh + off);
            al[m] = *reinterpret_cast<const bf16x8*>(lAl + off);
        }
#pragma unroll
        for (int n = 0; n < 4; n++) {
            int off = (wn * 64 + n * 16 + lr) * 32 + lg * 8;
            bh[n] = *reinterpret_cast<const bf16x8*>(lBh + off);
            bl[n] = *reinterpret_cast<const bf16x8*>(lBl + off);
        }
#pragma unroll
        for (int m = 0; m < 4; m++) {
#pragma unroll
            for (int n = 0; n < 4; n++) {
                acc[m][n] = mfma16(ah[m], bh[n], acc[m][n]);
                acc[m][n] = mfma16(ah[m], bl[n], acc[m][n]);
                acc[m][n] = mfma16(al[m], bh[n], acc[m][n]);
            }
        }
    }

    // epilogue
    const int row0 = m0 + wm * 64, col0 = n0 + wn * 64;
#pragma unroll
    for (int m = 0; m < 4; m++) {
#pragma unroll
        for (int n = 0; n < 4; n++) {
#pragma unroll
            for (int r = 0; r < 4; r++) {
                int row = row0 + m * 16 + lg * 4 + r;
                int col = col0 + n * 16 + lr;
                float cur = acc[m][n][r] + bias[col];
                if (MODE < 3) {
                    // LIF: 4 steps, subtract reset (detached), spike after update
                    float mem = 0.f;
                    int cnt = 0;
#pragma unroll
                    for (int tt = 0; tt < 4; tt++) {
                        float reset = (mem > 1.f) ? 1.f : 0.f;
                        mem = 0.95f * mem;
                        mem = mem + cur;
                        mem = mem - reset;
                        cnt += (mem > 1.f) ? 1 : 0;
                    }
                    u16 agg = f2bf((float)cnt * 0.25f);
                    int b = row >> 11, s = row & 2047;
                    int h = col >> 6, d = col & 63;
                    size_t idx;
                    if (MODE == 2)
                        idx = ((size_t)(b * H_ + h) * HD_ + d) * S_ + s;  // [bh][d][s]
                    else
                        idx = ((size_t)(b * H_ + h) * S_ + s) * HD_ + d;  // [bh][s][d]
                    ((u16*)outp)[idx] = agg;
                } else {
                    ((float*)outp)[(size_t)row * D_ + col] = cur;
                }
            }
        }
    }
}

// ---------------------------------------------------------------------------
// Attention: per block (q-tile of 128, one bh). 4 waves x 32 q-rows.
// No online max needed: scores in [0,8]; p = exp(s/8 - 4).
// Denominator via ones-operand MFMA on the SAME bf16 P (errors cancel).
// ---------------------------------------------------------------------------
__global__ __launch_bounds__(256, 2)
void attn_kernel(const u16* __restrict__ qa, const u16* __restrict__ ka,
                 const u16* __restrict__ vt,
                 u16* __restrict__ ohi, u16* __restrict__ olo) {
    __shared__ __align__(16) u16 Kt[64 * 64];
    __shared__ __align__(16) u16 Vt[64 * 64];
    __shared__ __align__(16) u16 Pt[4][32 * 64];

    const int t = threadIdx.x;
    const int wid = t >> 6, lane = t & 63;
    const int lr = lane & 15, lg = lane >> 4;
    const int bh = blockIdx.y;
    const int q0 = blockIdx.x * 128;

    const u16* qbase = qa + (size_t)bh * S_ * HD_;
    const u16* kbase = ka + (size_t)bh * S_ * HD_;
    const u16* vbase = vt + (size_t)bh * HD_ * S_;

    // Q fragments stay in registers for the whole K loop
    bf16x8 qf[2][2];
#pragma unroll
    for (int m = 0; m < 2; m++)
#pragma unroll
        for (int kc = 0; kc < 2; kc++) {
            int row = q0 + wid * 32 + m * 16 + lr;
            qf[m][kc] = *reinterpret_cast<const bf16x8*>(
                qbase + (size_t)row * HD_ + kc * 32 + lg * 8);
        }

    bf16x8 ones;
#pragma unroll
    for (int j = 0; j < 8; j++) ones[j] = (__bf16)1.0f;

    f32x4 oacc[2][4] = {};
    f32x4 ssum[2] = {};
    u16* myP = &Pt[wid][0];

    for (int kt = 0; kt < 32; ++kt) {
        // issue next tile's global loads early
        uint4 rk[2], rv[2];
#pragma unroll
        for (int p = 0; p < 2; p++) {
            int idx = t + p * 256;
            int row = idx >> 3, sl = idx & 7;
            rk[p] = *reinterpret_cast<const uint4*>(
                kbase + (size_t)(kt * 64 + row) * HD_ + sl * 8);
            rv[p] = *reinterpret_cast<const uint4*>(
                vbase + (size_t)row * S_ + kt * 64 + sl * 8);
        }
        __syncthreads();  // all waves done reading previous Kt/Vt
#pragma unroll
        for (int p = 0; p < 2; p++) {
            int idx = t + p * 256;
            int row = idx >> 3, sl = idx & 7;
            *reinterpret_cast<uint4*>(&Kt[row * 64 + ((sl ^ (row & 7)) * 8)]) = rk[p];
            *reinterpret_cast<uint4*>(&Vt[row * 64 + ((sl ^ (row & 7)) * 8)]) = rv[p];
        }
        __syncthreads();

        // S = Q K^T  (exact in bf16 MFMA: operands are multiples of 1/4)
        f32x4 sacc[2][4] = {};
#pragma unroll
        for (int n = 0; n < 4; n++) {
            int row = n * 16 + lr;
#pragma unroll
            for (int kc = 0; kc < 2; kc++) {
                int sl = kc * 4 + lg;
                bf16x8 kb = *reinterpret_cast<const bf16x8*>(
                    &Kt[row * 64 + ((sl ^ (row & 7)) * 8)]);
                sacc[0][n] = mfma16(qf[0][kc], kb, sacc[0][n]);
                sacc[1][n] = mfma16(qf[1][kc], kb, sacc[1][n]);
            }
        }
        // P = exp(s/8 - 4), write to wave-private swizzled LDS tile
#pragma unroll
        for (int m = 0; m < 2; m++)
#pragma unroll
            for (int n = 0; n < 4; n++)
#pragma unroll
                for (int r = 0; r < 4; r++) {
                    float p = __expf(sacc[m][n][r] * 0.125f - 4.0f);
                    int prow = m * 16 + lg * 4 + r;
                    int pbyte = prow * 128 + (((n * 16 + lr) * 2) ^ ((prow & 7) << 4));
                    *reinterpret_cast<u16*>(reinterpret_cast<char*>(myP) + pbyte) = f2bf(p);
                }
        // PV + row-sum (wave-private P: same-wave DS ordering suffices)
        bf16x8 pa[2][2];
#pragma unroll
        for (int m = 0; m < 2; m++)
#pragma unroll
            for (int kc = 0; kc < 2; kc++) {
                int row = m * 16 + lr;
                int sl = kc * 4 + lg;
                pa[m][kc] = *reinterpret_cast<const bf16x8*>(
                    &myP[row * 64 + ((sl ^ (row & 7)) * 8)]);
            }
#pragma unroll
        for (int n = 0; n < 4; n++) {
            int row = n * 16 + lr;  // row of Vt = d index
#pragma unroll
            for (int kc = 0; kc < 2; kc++) {
                int sl = kc * 4 + lg;
                bf16x8 vb = *reinterpret_cast<const bf16x8*>(
                    &Vt[row * 64 + ((sl ^ (row & 7)) * 8)]);
                oacc[0][n] = mfma16(pa[0][kc], vb, oacc[0][n]);
                oacc[1][n] = mfma16(pa[1][kc], vb, oacc[1][n]);
            }
        }
#pragma unroll
        for (int m = 0; m < 2; m++)
#pragma unroll
            for (int kc = 0; kc < 2; kc++)
                ssum[m] = mfma16(pa[m][kc], ones, ssum[m]);
    }

    // epilogue: divide, split to hi/lo bf16 for the o-projection
    const int b = bh >> 4, h = bh & 15;
#pragma unroll
    for (int m = 0; m < 2; m++)
#pragma unroll
        for (int n = 0; n < 4; n++)
#pragma unroll
            for (int r = 0; r < 4; r++) {
                int q = q0 + wid * 32 + m * 16 + lg * 4 + r;
                int d = n * 16 + lr;
                float v = oacc[m][n][r] / ssum[m][r];
                size_t gi = (size_t)(b * S_ + q) * D_ + h * 64 + d;
                u16 hi = f2bf(v);
                u16 lo = f2bf(v - bf2f(hi));
                ohi[gi] = hi;
                olo[gi] = lo;
            }
}

// ---------------------------------------------------------------------------
extern "C" void kernel_launch(void* const* d_in, const int* in_sizes, int n_in,
                              void* d_out, int out_size, void* d_ws, size_t ws_size,
                              hipStream_t stream) {
    (void)in_sizes; (void)n_in; (void)out_size; (void)ws_size;
    const float* x  = (const float*)d_in[0];
    const float* qw = (const float*)d_in[1];
    const float* qb = (const float*)d_in[2];
    const float* kw = (const float*)d_in[3];
    const float* kb = (const float*)d_in[4];
    const float* vw = (const float*)d_in[5];
    const float* vb = (const float*)d_in[6];
    const float* ow = (const float*)d_in[7];
    const float* ob = (const float*)d_in[8];

    u16* ws = (u16*)d_ws;
    const size_t C = 4194304;  // 4096*1024 elements
    u16* xhi = ws + 0 * C;
    u16* xlo = ws + 1 * C;
    u16* wth = ws + 2 * C;  // 4 transposed hi weights, 1M elems each
    u16* wtl = ws + 3 * C;
    u16* qag = ws + 4 * C;
    u16* kag = ws + 5 * C;
    u16* vtg = ws + 6 * C;
    u16* ohi = ws + 7 * C;
    u16* olo = ws + 8 * C;

    split_x_kernel<<<4096, 256, 0, stream>>>(x, xhi, xlo, (int)(C / 4));
    const float* wsrc[4] = {qw, kw, vw, ow};
    for (int i = 0; i < 4; i++)
        split_w_kernel<<<dim3(32, 32), dim3(32, 8), 0, stream>>>(
            wsrc[i], wth + (size_t)i * 1048576, wtl + (size_t)i * 1048576);

    gemm_kernel<0><<<dim3(8, 32), 256, 0, stream>>>(xhi, xlo, wth + 0 * 1048576,
                                                    wtl + 0 * 1048576, qb, qag);
    gemm_kernel<1><<<dim3(8, 32), 256, 0, stream>>>(xhi, xlo, wth + 1 * 1048576,
                                                    wtl + 1 * 1048576, kb, kag);
    gemm_kernel<2><<<dim3(8, 32), 256, 0, stream>>>(xhi, xlo, wth + 2 * 1048576,
                                                    wtl + 2 * 1048576, vb, vtg);
    attn_kernel<<<dim3(16, 32), 256, 0, stream>>>(qag, kag, vtg, ohi, olo);
    gemm_kernel<3><<<dim3(8, 32), 256, 0, stream>>>(ohi, olo, wth + 3 * 1048576,
                                                    wtl + 3 * 1048576, ob, d_out);
}

// Round 2
// 217.234 us; speedup vs baseline: 2.2316x; 2.2316x over previous
//
#include <hip/hip_runtime.h>
#include <hip/hip_bf16.h>
#include <stdint.h>

typedef unsigned short u16;
typedef unsigned int u32;
typedef __bf16 bf16x8 __attribute__((ext_vector_type(8)));
typedef float f32x4 __attribute__((ext_vector_type(4)));

#define B_   2
#define S_   2048
#define D_   1024
#define H_   16
#define HD_  64

__device__ __forceinline__ u16 f2bf(float f) {
    u32 u = __float_as_uint(f);
    u32 r = (u + 0x7FFFu + ((u >> 16) & 1u)) >> 16;   // RNE; inputs never NaN/Inf
    return (u16)r;
}
__device__ __forceinline__ float bf2f(u16 s) { return __uint_as_float(((u32)s) << 16); }

__device__ __forceinline__ f32x4 mfma16(bf16x8 a, bf16x8 b, f32x4 c) {
    return __builtin_amdgcn_mfma_f32_16x16x32_bf16(a, b, c, 0, 0, 0);
}

// async global->LDS, 16B per lane; lds dest must be wave-uniform base (+lane*16)
__device__ __forceinline__ void gl16(const u16* g, u16* l) {
    __builtin_amdgcn_global_load_lds(
        (const __attribute__((address_space(1))) void*)g,
        (__attribute__((address_space(3))) void*)l, 16, 0, 0);
}

// ---------------------------------------------------------------------------
// Split fp32 -> (hi, lo) bf16 pair, elementwise (for x)
// ---------------------------------------------------------------------------
__global__ void split_x_kernel(const float* __restrict__ x,
                               u16* __restrict__ hi, u16* __restrict__ lo, int n4) {
    int i = blockIdx.x * blockDim.x + threadIdx.x;
    if (i >= n4) return;
    float4 v = reinterpret_cast<const float4*>(x)[i];
    u16 h0 = f2bf(v.x), h1 = f2bf(v.y), h2 = f2bf(v.z), h3 = f2bf(v.w);
    u16 l0 = f2bf(v.x - bf2f(h0)), l1 = f2bf(v.y - bf2f(h1));
    u16 l2 = f2bf(v.z - bf2f(h2)), l3 = f2bf(v.w - bf2f(h3));
    uint2 hp, lp;
    hp.x = (u32)h0 | ((u32)h1 << 16); hp.y = (u32)h2 | ((u32)h3 << 16);
    lp.x = (u32)l0 | ((u32)l1 << 16); lp.y = (u32)l2 | ((u32)l3 << 16);
    reinterpret_cast<uint2*>(hi)[i] = hp;
    reinterpret_cast<uint2*>(lo)[i] = lp;
}

// ---------------------------------------------------------------------------
// Split + transpose a [in=1024][out=1024] weight -> wT hi/lo [out][in]
// ---------------------------------------------------------------------------
__global__ void split_w_kernel(const float* __restrict__ w,
                               u16* __restrict__ thi, u16* __restrict__ tlo) {
    __shared__ float tile[32][33];
    int bi = blockIdx.y;   // input-dim block
    int bj = blockIdx.x;   // output-dim block
    int tx = threadIdx.x;  // 0..31
    int ty = threadIdx.y;  // 0..7
#pragma unroll
    for (int k = 0; k < 4; k++) {
        int r = ty + k * 8;
        tile[r][tx] = w[(size_t)(bi * 32 + r) * D_ + bj * 32 + tx];
    }
    __syncthreads();
#pragma unroll
    for (int k = 0; k < 4; k++) {
        int r = ty + k * 8;
        float v = tile[tx][r];
        u16 h = f2bf(v);
        u16 l = f2bf(v - bf2f(h));
        size_t idx = (size_t)(bj * 32 + r) * D_ + bi * 32 + tx;
        thi[idx] = h;
        tlo[idx] = l;
    }
}

// ---------------------------------------------------------------------------
// Split-bf16 GEMM: C = A @ B^T(stored row-major [N][K]) with hi/lo operands.
// MODE 0: fused QKV proj (+LIF).  N = 3072, per-128-col-tile proj select.
//         proj 0/1 (q/k) -> [bh][s][d];  proj 2 (v) -> [bh][d][s] transposed.
// MODE 3: o proj (+bias, fp32 out [4096][1024]).
// Tile BM x 128, BK=32, 4 waves (2x2, each (BM/2) x 64).
// Staging: global_load_lds w=16, linear LDS dest, SOURCE-swizzled chunks
// (chunk ^= (row>>1)&3) so frag ds_read_b128 hits all 8 bank-quads.
// ---------------------------------------------------------------------------
template <int MODE, int BM>
__global__ __launch_bounds__(256, 2)
void gemm_kernel(const u16* __restrict__ Ahg, const u16* __restrict__ Alg,
                 const u16* __restrict__ Bhg, const u16* __restrict__ Blg,
                 const float* __restrict__ b0, const float* __restrict__ b1,
                 const float* __restrict__ b2,
                 u16* __restrict__ o0, u16* __restrict__ o1, u16* __restrict__ o2,
                 float* __restrict__ o3) {
    constexpr int AMF = BM / 32;    // A frags per wave
    constexpr int APASS = BM / 64;  // 256-thread staging passes per A buffer
    __shared__ __align__(16) u16 lAh[BM * 32];
    __shared__ __align__(16) u16 lAl[BM * 32];
    __shared__ __align__(16) u16 lBh[128 * 32];
    __shared__ __align__(16) u16 lBl[128 * 32];

    const int t = threadIdx.x;
    const int m0 = blockIdx.y * BM;
    const int n0 = blockIdx.x * 128;
    const int wid = t >> 6, lane = t & 63;
    const int wm = wid >> 1, wn = wid & 1;
    const int lr = lane & 15, lg = lane >> 4;

    f32x4 acc[AMF][4] = {};

    for (int kk = 0; kk < 32; ++kk) {
        const int k0 = kk * 32;
        // ---- stage tile kk (async DMA, linear dest, swizzled source) ----
#pragma unroll
        for (int p = 0; p < APASS; p++) {
            int idx = p * 256 + wid * 64 + lane;
            int row = idx >> 2, sl = idx & 3;
            int slx = sl ^ ((row >> 1) & 3);
            size_t ga = (size_t)(m0 + row) * D_ + k0 + slx * 8;
            u16* lbase = (u16*)(lAh + (size_t)(p * 256 + wid * 64) * 8);
            gl16(Ahg + ga, lbase);
            gl16(Alg + ga, lAl + (size_t)(p * 256 + wid * 64) * 8);
        }
#pragma unroll
        for (int p = 0; p < 2; p++) {
            int idx = p * 256 + wid * 64 + lane;
            int row = idx >> 2, sl = idx & 3;
            int slx = sl ^ ((row >> 1) & 3);
            size_t gb = (size_t)(n0 + row) * D_ + k0 + slx * 8;
            gl16(Bhg + gb, lBh + (size_t)(p * 256 + wid * 64) * 8);
            gl16(Blg + gb, lBl + (size_t)(p * 256 + wid * 64) * 8);
        }
        __syncthreads();  // compiler drains vmcnt(0) before barrier -> LDS valid

        bf16x8 ah[AMF], al[AMF], bh[4], bl[4];
#pragma unroll
        for (int m = 0; m < AMF; m++) {
            int row = wm * (BM / 2) + m * 16 + lr;
            int off = row * 32 + (lg ^ ((row >> 1) & 3)) * 8;
            ah[m] = *reinterpret_cast<const bf16x8*>(lAh + off);
            al[m] = *reinterpret_cast<const bf16x8*>(lAl + off);
        }
#pragma unroll
        for (int n = 0; n < 4; n++) {
            int row = wn * 64 + n * 16 + lr;
            int off = row * 32 + (lg ^ ((row >> 1) & 3)) * 8;
            bh[n] = *reinterpret_cast<const bf16x8*>(lBh + off);
            bl[n] = *reinterpret_cast<const bf16x8*>(lBl + off);
        }
#pragma unroll
        for (int m = 0; m < AMF; m++) {
#pragma unroll
            for (int n = 0; n < 4; n++) {
                acc[m][n] = mfma16(ah[m], bh[n], acc[m][n]);
                acc[m][n] = mfma16(ah[m], bl[n], acc[m][n]);
                acc[m][n] = mfma16(al[m], bh[n], acc[m][n]);
            }
        }
        __syncthreads();  // readers done before next stage overwrites
    }

    // ---- epilogue ----
    const int row0 = m0 + wm * (BM / 2);
    const int col0f = n0 + wn * 64;
    const int proj = col0f >> 10;  // 0..2 (MODE 0); 0 (MODE 3)
    const float* bias = (MODE == 3) ? b0 : (proj == 0 ? b0 : (proj == 1 ? b1 : b2));
    u16* dst = (proj == 0) ? o0 : (proj == 1) ? o1 : o2;
    const int colp0 = col0f & 1023;
#pragma unroll
    for (int m = 0; m < AMF; m++) {
#pragma unroll
        for (int n = 0; n < 4; n++) {
#pragma unroll
            for (int r = 0; r < 4; r++) {
                int row = row0 + m * 16 + lg * 4 + r;
                int colp = colp0 + n * 16 + lr;
                float cur = acc[m][n][r] + bias[colp];
                if (MODE == 0) {
                    // LIF: 4 steps, subtract reset (detached), spike after update
                    float mem = 0.f;
                    int cnt = 0;
#pragma unroll
                    for (int tt = 0; tt < 4; tt++) {
                        float reset = (mem > 1.f) ? 1.f : 0.f;
                        mem = 0.95f * mem;
                        mem = mem + cur;
                        mem = mem - reset;
                        cnt += (mem > 1.f) ? 1 : 0;
                    }
                    u16 agg = f2bf((float)cnt * 0.25f);
                    int b = row >> 11, s = row & 2047;
                    int h = colp >> 6, d = colp & 63;
                    size_t idx;
                    if (proj == 2)
                        idx = ((size_t)(b * H_ + h) * HD_ + d) * S_ + s;  // [bh][d][s]
                    else
                        idx = ((size_t)(b * H_ + h) * S_ + s) * HD_ + d;  // [bh][s][d]
                    dst[idx] = agg;
                } else {
                    o3[(size_t)row * D_ + colp] = cur;
                }
            }
        }
    }
}

// ---------------------------------------------------------------------------
// Attention: per block (q-tile of 128, one bh). 4 waves x 32 q-rows.
// No online max needed: scores in [0,8]; p = exp(s/8 - 4).
// Denominator via ones-operand MFMA on the SAME bf16 P (errors cancel).
// ---------------------------------------------------------------------------
__global__ __launch_bounds__(256, 2)
void attn_kernel(const u16* __restrict__ qa, const u16* __restrict__ ka,
                 const u16* __restrict__ vt,
                 u16* __restrict__ ohi, u16* __restrict__ olo) {
    __shared__ __align__(16) u16 Kt[64 * 64];
    __shared__ __align__(16) u16 Vt[64 * 64];
    __shared__ __align__(16) u16 Pt[4][32 * 64];

    const int t = threadIdx.x;
    const int wid = t >> 6, lane = t & 63;
    const int lr = lane & 15, lg = lane >> 4;
    const int bh = blockIdx.y;
    const int q0 = blockIdx.x * 128;

    const u16* qbase = qa + (size_t)bh * S_ * HD_;
    const u16* kbase = ka + (size_t)bh * S_ * HD_;
    const u16* vbase = vt + (size_t)bh * HD_ * S_;

    // Q fragments stay in registers for the whole K loop
    bf16x8 qf[2][2];
#pragma unroll
    for (int m = 0; m < 2; m++)
#pragma unroll
        for (int kc = 0; kc < 2; kc++) {
            int row = q0 + wid * 32 + m * 16 + lr;
            qf[m][kc] = *reinterpret_cast<const bf16x8*>(
                qbase + (size_t)row * HD_ + kc * 32 + lg * 8);
        }

    bf16x8 ones;
#pragma unroll
    for (int j = 0; j < 8; j++) ones[j] = (__bf16)1.0f;

    f32x4 oacc[2][4] = {};
    f32x4 ssum[2] = {};
    u16* myP = &Pt[wid][0];

    for (int kt = 0; kt < 32; ++kt) {
        // issue next tile's global loads early
        uint4 rk[2], rv[2];
#pragma unroll
        for (int p = 0; p < 2; p++) {
            int idx = t + p * 256;
            int row = idx >> 3, sl = idx & 7;
            rk[p] = *reinterpret_cast<const uint4*>(
                kbase + (size_t)(kt * 64 + row) * HD_ + sl * 8);
            rv[p] = *reinterpret_cast<const uint4*>(
                vbase + (size_t)row * S_ + kt * 64 + sl * 8);
        }
        __syncthreads();  // all waves done reading previous Kt/Vt
#pragma unroll
        for (int p = 0; p < 2; p++) {
            int idx = t + p * 256;
            int row = idx >> 3, sl = idx & 7;
            *reinterpret_cast<uint4*>(&Kt[row * 64 + ((sl ^ (row & 7)) * 8)]) = rk[p];
            *reinterpret_cast<uint4*>(&Vt[row * 64 + ((sl ^ (row & 7)) * 8)]) = rv[p];
        }
        __syncthreads();

        // S = Q K^T  (exact in bf16 MFMA: operands are multiples of 1/4)
        f32x4 sacc[2][4] = {};
#pragma unroll
        for (int n = 0; n < 4; n++) {
            int row = n * 16 + lr;
#pragma unroll
            for (int kc = 0; kc < 2; kc++) {
                int sl = kc * 4 + lg;
                bf16x8 kb = *reinterpret_cast<const bf16x8*>(
                    &Kt[row * 64 + ((sl ^ (row & 7)) * 8)]);
                sacc[0][n] = mfma16(qf[0][kc], kb, sacc[0][n]);
                sacc[1][n] = mfma16(qf[1][kc], kb, sacc[1][n]);
            }
        }
        // P = exp(s/8 - 4), write to wave-private swizzled LDS tile
#pragma unroll
        for (int m = 0; m < 2; m++)
#pragma unroll
            for (int n = 0; n < 4; n++)
#pragma unroll
                for (int r = 0; r < 4; r++) {
                    float p = __expf(sacc[m][n][r] * 0.125f - 4.0f);
                    int prow = m * 16 + lg * 4 + r;
                    int pbyte = prow * 128 + (((n * 16 + lr) * 2) ^ ((prow & 7) << 4));
                    *reinterpret_cast<u16*>(reinterpret_cast<char*>(myP) + pbyte) = f2bf(p);
                }
        // PV + row-sum (wave-private P: same-wave DS ordering suffices)
        bf16x8 pa[2][2];
#pragma unroll
        for (int m = 0; m < 2; m++)
#pragma unroll
            for (int kc = 0; kc < 2; kc++) {
                int row = m * 16 + lr;
                int sl = kc * 4 + lg;
                pa[m][kc] = *reinterpret_cast<const bf16x8*>(
                    &myP[row * 64 + ((sl ^ (row & 7)) * 8)]);
            }
#pragma unroll
        for (int n = 0; n < 4; n++) {
            int row = n * 16 + lr;  // row of Vt = d index
#pragma unroll
            for (int kc = 0; kc < 2; kc++) {
                int sl = kc * 4 + lg;
                bf16x8 vb = *reinterpret_cast<const bf16x8*>(
                    &Vt[row * 64 + ((sl ^ (row & 7)) * 8)]);
                oacc[0][n] = mfma16(pa[0][kc], vb, oacc[0][n]);
                oacc[1][n] = mfma16(pa[1][kc], vb, oacc[1][n]);
            }
        }
#pragma unroll
        for (int m = 0; m < 2; m++)
#pragma unroll
            for (int kc = 0; kc < 2; kc++)
                ssum[m] = mfma16(pa[m][kc], ones, ssum[m]);
    }

    // epilogue: divide, split to hi/lo bf16 for the o-projection
    const int b = bh >> 4, h = bh & 15;
#pragma unroll
    for (int m = 0; m < 2; m++)
#pragma unroll
        for (int n = 0; n < 4; n++)
#pragma unroll
            for (int r = 0; r < 4; r++) {
                int q = q0 + wid * 32 + m * 16 + lg * 4 + r;
                int d = n * 16 + lr;
                float v = oacc[m][n][r] / ssum[m][r];
                size_t gi = (size_t)(b * S_ + q) * D_ + h * 64 + d;
                u16 hi = f2bf(v);
                u16 lo = f2bf(v - bf2f(hi));
                ohi[gi] = hi;
                olo[gi] = lo;
            }
}

// ---------------------------------------------------------------------------
extern "C" void kernel_launch(void* const* d_in, const int* in_sizes, int n_in,
                              void* d_out, int out_size, void* d_ws, size_t ws_size,
                              hipStream_t stream) {
    (void)in_sizes; (void)n_in; (void)out_size; (void)ws_size;
    const float* x  = (const float*)d_in[0];
    const float* qw = (const float*)d_in[1];
    const float* qb = (const float*)d_in[2];
    const float* kw = (const float*)d_in[3];
    const float* kb = (const float*)d_in[4];
    const float* vw = (const float*)d_in[5];
    const float* vb = (const float*)d_in[6];
    const float* ow = (const float*)d_in[7];
    const float* ob = (const float*)d_in[8];

    u16* ws = (u16*)d_ws;
    const size_t C = 4194304;  // 4096*1024 elements
    u16* xhi = ws + 0 * C;
    u16* xlo = ws + 1 * C;
    u16* wth = ws + 2 * C;  // 4 transposed hi weights [out][in], 1M elems each (q,k,v,o)
    u16* wtl = ws + 3 * C;
    u16* qag = ws + 4 * C;
    u16* kag = ws + 5 * C;
    u16* vtg = ws + 6 * C;
    u16* ohi = ws + 7 * C;
    u16* olo = ws + 8 * C;

    split_x_kernel<<<4096, 256, 0, stream>>>(x, xhi, xlo, (int)(C / 4));
    const float* wsrc[4] = {qw, kw, vw, ow};
    for (int i = 0; i < 4; i++)
        split_w_kernel<<<dim3(32, 32), dim3(32, 8), 0, stream>>>(
            wsrc[i], wth + (size_t)i * 1048576, wtl + (size_t)i * 1048576);

    // fused QKV projection: A=[4096][1024] x B^T=[3072][1024], LIF epilogue
    gemm_kernel<0, 128><<<dim3(24, 32), 256, 0, stream>>>(
        xhi, xlo, wth, wtl, qb, kb, vb, qag, kag, vtg, nullptr);
    attn_kernel<<<dim3(16, 32), 256, 0, stream>>>(qag, kag, vtg, ohi, olo);
    // o-projection: BM=64 -> 512 blocks for 2 blocks/CU
    gemm_kernel<3, 64><<<dim3(8, 64), 256, 0, stream>>>(
        ohi, olo, wth + 3 * 1048576, wtl + 3 * 1048576, ob, nullptr, nullptr,
        nullptr, nullptr, nullptr, (float*)d_out);
}